// Round 9
// baseline (4145.171 us; speedup 1.0000x reference)
//
#include <hip/hip_runtime.h>
#include <hip/hip_bf16.h>
#include <math.h>

#define B_ 128
#define S_ 64
#define D_ 512
#define H_ 256
#define SEL_ 128
#define MLPD_ 1024
#define CLS_ 3

typedef __attribute__((ext_vector_type(8))) short bf16x8;
typedef __attribute__((ext_vector_type(4))) float f32x4;

__device__ __forceinline__ float sigf(float x) { return 1.f / (1.f + expf(-x)); }

// fp32 -> bf16 round-to-nearest-even (bit trick; no inf/nan in this workload)
__device__ __forceinline__ ushort bf16r(float x) {
    uint u = __float_as_uint(x);
    return (ushort)((u + 0x7fffu + ((u >> 16) & 1u)) >> 16);
}
__device__ __forceinline__ float bf2f(ushort h) { return __uint_as_float(((uint)h) << 16); }

// XCD-chunk swizzle (T1, m204 bijective): XCD k = bid%8 owns a contiguous chunk of w.
__device__ __forceinline__ int xcd_chunk(int bid, int nb) {
    int q = nb >> 3, r = nb & 7;
    int xcd = bid & 7, j = bid >> 3;
    return (xcd < r ? xcd * (q + 1) : r * (q + 1) + (xcd - r) * q) + j;
}

// ---------------- embedding gather + bf16 hi/lo split (state := hi+lo) ----------------
__global__ __launch_bounds__(256) void k_embed(const int* __restrict__ sent,
                                               const float* __restrict__ emb,
                                               ushort* __restrict__ oh,
                                               ushort* __restrict__ ol) {
    int idx = blockIdx.x * 256 + threadIdx.x;      // B*S*D/4 float4 slots
    int row = idx >> 7;
    int k4 = (idx & 127) << 2;
    int tok = sent[row];
    float4 v = *(const float4*)(emb + (size_t)tok * D_ + k4);
    ushort4 h, l;
    h.x = bf16r(v.x); l.x = bf16r(v.x - bf2f(h.x));
    h.y = bf16r(v.y); l.y = bf16r(v.y - bf2f(h.y));
    h.z = bf16r(v.z); l.z = bf16r(v.z - bf2f(h.z));
    h.w = bf16r(v.w); l.w = bf16r(v.w - bf2f(h.w));
    *(ushort4*)(oh + (size_t)row * D_ + k4) = h;
    *(ushort4*)(ol + (size_t)row * D_ + k4) = l;
}

// ---------------- transpose + split: dst[n][k] = src[k][n], K,N multiples of 64 ----------------
__global__ __launch_bounds__(256) void k_tsplit(const float* __restrict__ src,
                                                ushort* __restrict__ dh,
                                                ushort* __restrict__ dl,
                                                int K, int N) {
    __shared__ float t[64][65];
    int n0 = blockIdx.x * 64, k0 = blockIdx.y * 64;
    int tx = threadIdx.x & 63, ty = threadIdx.x >> 6;
    for (int i = ty; i < 64; i += 4)
        t[i][tx] = src[(size_t)(k0 + i) * N + n0 + tx];
    __syncthreads();
    for (int i = ty; i < 64; i += 4) {
        float v = t[tx][i];
        ushort h = bf16r(v);
        size_t o = (size_t)(n0 + i) * K + k0 + tx;
        dh[o] = h;
        dl[o] = bf16r(v - bf2f(h));
    }
}

// ---------------- selection hidden + logits, fused (LDS-staged MFMA, bf16x2 3-term) ----------------
// Block = 64 rows x 128 cols (full sel width), K=1024, BK=32. Epilogue computes
// logits[g] = sum_c tanh(acc+b1[c]) * W2[c] + b2 directly -> no hid buffer.
__global__ __launch_bounds__(256) void k_sellogit(const ushort* __restrict__ sh,
                                                  const ushort* __restrict__ sl,
                                                  const ushort* __restrict__ w1h,
                                                  const ushort* __restrict__ w1l,
                                                  const float* __restrict__ b1,
                                                  const float* __restrict__ W2,
                                                  const float* __restrict__ b2,
                                                  float* __restrict__ logits,
                                                  int N, int M, int cdiv) {
    __shared__ __align__(16) ushort sAm[2][64][40];
    __shared__ __align__(16) ushort sBm[2][128][40];
    __shared__ int rb[64];
    __shared__ float lpart[2][64];
    int w = xcd_chunk(blockIdx.x, gridDim.x);
    int r0 = w * 64;
    int tid = threadIdx.x, l = tid & 63, wid = tid >> 6;
    int wm = wid >> 1, wn = wid & 1;
    int lr = l & 15, lk = (l >> 4) << 3;

    if (tid < 64) {
        int g = r0 + tid;
        int q = (int)(((long long)g * cdiv) >> 20);      // g / N
        rb[tid] = (g + q) * 512;
    }
    __syncthreads();

    float bias[4], w2v[4];
#pragma unroll
    for (int tj = 0; tj < 4; tj++) {
        int c = wn * 64 + tj * 16 + lr;
        bias[tj] = b1[c];
        w2v[tj] = W2[c];
    }

    const ushort* aSrc[2]; ushort* aDst[2];
#pragma unroll
    for (int i = 0; i < 2; i++) {
        int idx = tid + i * 256;
        int p = idx >> 8, rem = idx & 255;
        int r = rem >> 2, s = rem & 3;
        aSrc[i] = (p ? sl : sh) + rb[r] + s * 8;
        aDst[i] = &sAm[p][r][s * 8];
    }
    const ushort* bSrc[4]; ushort* bDst[4];
#pragma unroll
    for (int j = 0; j < 4; j++) {
        int idx = tid + j * 256;
        int p = (idx >= 512) ? 1 : 0;
        int rem = idx - p * 512;
        int br = rem >> 2, s = rem & 3;
        bSrc[j] = (p ? w1l : w1h) + br * 1024 + s * 8;
        bDst[j] = &sBm[p][br][s * 8];
    }

    f32x4 z = {0.f, 0.f, 0.f, 0.f};
    f32x4 acc[2][4] = {{z, z, z, z}, {z, z, z, z}};
    bf16x8 gA[2], gB[4];

#define SSTAGE_LOAD(kk) do {                                               \
        _Pragma("unroll")                                                  \
        for (int i = 0; i < 2; i++) gA[i] = *(const bf16x8*)(aSrc[i] + (kk)); \
        _Pragma("unroll")                                                  \
        for (int j = 0; j < 4; j++) gB[j] = *(const bf16x8*)(bSrc[j] + (kk)); \
    } while (0)
#define SSTAGE_WRITE() do {                                                \
        _Pragma("unroll")                                                  \
        for (int i = 0; i < 2; i++) *(bf16x8*)aDst[i] = gA[i];             \
        _Pragma("unroll")                                                  \
        for (int j = 0; j < 4; j++) *(bf16x8*)bDst[j] = gB[j];             \
    } while (0)

    SSTAGE_LOAD(0);
    SSTAGE_WRITE();
    __syncthreads();

    for (int ks = 0; ks < 32; ks++) {
        if (ks < 31) SSTAGE_LOAD((ks + 1) * 32);
        bf16x8 fa[2][2], fb[2][4];
#pragma unroll
        for (int t = 0; t < 2; t++) {
            int ar = wm * 32 + t * 16 + lr;
            fa[0][t] = *(const bf16x8*)&sAm[0][ar][lk];
            fa[1][t] = *(const bf16x8*)&sAm[1][ar][lk];
        }
#pragma unroll
        for (int tj = 0; tj < 4; tj++) {
            int bc = wn * 64 + tj * 16 + lr;
            fb[0][tj] = *(const bf16x8*)&sBm[0][bc][lk];
            fb[1][tj] = *(const bf16x8*)&sBm[1][bc][lk];
        }
#pragma unroll
        for (int ti = 0; ti < 2; ti++)
#pragma unroll
            for (int tj = 0; tj < 4; tj++) {
                acc[ti][tj] = __builtin_amdgcn_mfma_f32_16x16x32_bf16(fa[0][ti], fb[0][tj], acc[ti][tj], 0, 0, 0);
                acc[ti][tj] = __builtin_amdgcn_mfma_f32_16x16x32_bf16(fa[0][ti], fb[1][tj], acc[ti][tj], 0, 0, 0);
                acc[ti][tj] = __builtin_amdgcn_mfma_f32_16x16x32_bf16(fa[1][ti], fb[0][tj], acc[ti][tj], 0, 0, 0);
            }
        __syncthreads();
        if (ks < 31) {
            SSTAGE_WRITE();
            __syncthreads();
        }
    }
#undef SSTAGE_LOAD
#undef SSTAGE_WRITE

    // epilogue: per-thread partial logits, reduce over the 16 col-lanes, combine warps via LDS
    float part[2][4];
#pragma unroll
    for (int ti = 0; ti < 2; ti++)
#pragma unroll
        for (int r = 0; r < 4; r++) {
            float s = 0.f;
#pragma unroll
            for (int tj = 0; tj < 4; tj++)
                s += tanhf(acc[ti][tj][r] + bias[tj]) * w2v[tj];
            part[ti][r] = s;
        }
#pragma unroll
    for (int off = 1; off < 16; off <<= 1)
#pragma unroll
        for (int ti = 0; ti < 2; ti++)
#pragma unroll
            for (int r = 0; r < 4; r++)
                part[ti][r] += __shfl_xor(part[ti][r], off);
    if ((l & 15) == 0) {
#pragma unroll
        for (int ti = 0; ti < 2; ti++)
#pragma unroll
            for (int r = 0; r < 4; r++)
                lpart[wn][wm * 32 + ti * 16 + ((l >> 4) << 2) + r] = part[ti][r];
    }
    __syncthreads();
    if (tid < 64) {
        int g = r0 + tid;
        logits[g] = lpart[0][tid] + lpart[1][tid] + b2[0];
    }
}

// ---------------- fused softmax/cumsum + gates GEMM + treeLSTM + combine ----------------
// Prologue: stage this block's logits window to LDS; 64 threads compute (cl,cr,sel) per row.
// Then LDS-staged bf16x2 MFMA GEMM as in round 8.
__global__ __launch_bounds__(256) void k_compose(const ushort* __restrict__ sh,
                                                 const ushort* __restrict__ sl,
                                                 const ushort* __restrict__ wth,
                                                 const ushort* __restrict__ wtl,
                                                 const float* __restrict__ cbias,
                                                 const float* __restrict__ logits,
                                                 ushort* __restrict__ dh,
                                                 ushort* __restrict__ dl,
                                                 float* __restrict__ root,
                                                 int N, int M, int cdiv) {
    __shared__ __align__(16) ushort sAm[2][64][40];
    __shared__ __align__(16) ushort sBm[2][160][40];
    __shared__ int rb[64];
    __shared__ float slog[192];
    __shared__ float scoef[64][3];
    int w = xcd_chunk(blockIdx.x, gridDim.x);
    int cx = w & 7, ry = w >> 3;
    int tid = threadIdx.x, l = tid & 63, wid = tid >> 6;
    int wm = wid >> 1, wn = wid & 1;
    int r0 = ry * 64;
    int cb_blk = cx * 32;
    int cbw = cb_blk + wn * 16;
    int lr = l & 15, lk = (l >> 4) << 3;

    int blo = (int)(((long long)r0 * cdiv) >> 20);            // r0 / N
    int bhi = (int)(((long long)(r0 + 63) * cdiv) >> 20);     // (r0+63) / N
    int cnt = (bhi - blo + 1) * N;
    if (tid < 64) {
        int g = r0 + tid;
        int q = (int)(((long long)g * cdiv) >> 20);
        rb[tid] = (g + q) * 512;
    }
    if (tid < cnt) slog[tid] = logits[blo * N + tid];
    __syncthreads();

    if (tid < 64) {
        int g = r0 + tid;
        int b = (int)(((long long)g * cdiv) >> 20);
        int j = g - b * N;
        int o = (b - blo) * N;
        float mx = -1e30f;
        for (int k = 0; k < N; k++) mx = fmaxf(mx, slog[o + k]);
        float tot = 0.f, cs = 0.f, pj = 0.f;
        for (int k = 0; k < N; k++) {
            float e = expf(slog[o + k] - mx);
            tot += e;
            if (k <= j) cs += e;
            if (k == j) pj = e;
        }
        float inv = 1.f / tot;
        scoef[tid][0] = (tot - cs) * inv;   // copy_left
        scoef[tid][1] = (cs - pj) * inv;    // copy_right
        scoef[tid][2] = pj * inv;           // select
    }

    float bias[5];
#pragma unroll
    for (int gt = 0; gt < 5; gt++) bias[gt] = cbias[gt * 256 + cbw + lr];

    const ushort* aSrc[2]; ushort* aDst[2];
#pragma unroll
    for (int i = 0; i < 2; i++) {
        int idx = tid + i * 256;
        int p = idx >> 8, rem = idx & 255;
        int r = rem >> 2, s = rem & 3;
        aSrc[i] = (p ? sl : sh) + rb[r] + s * 8;
        aDst[i] = &sAm[p][r][s * 8];
    }
    const ushort* bSrc[5]; ushort* bDst[5];
#pragma unroll
    for (int j = 0; j < 5; j++) {
        int idx = tid + j * 256;
        int p = (idx >= 640) ? 1 : 0;
        int rem = idx - p * 640;
        int br = rem >> 2, s = rem & 3;
        int col = (br >> 5) * 256 + cb_blk + (br & 31);
        bSrc[j] = (p ? wtl : wth) + col * 512 + s * 8;
        bDst[j] = &sBm[p][br][s * 8];
    }

    f32x4 z = {0.f, 0.f, 0.f, 0.f};
    f32x4 acc[2][5] = {{z, z, z, z, z}, {z, z, z, z, z}};
    bf16x8 gA[2], gB[5];

#define CSTAGE_LOAD(kk) do {                                               \
        int koff_ = ((kk) < 256) ? (kk) : (kk) + 256;                      \
        _Pragma("unroll")                                                  \
        for (int i = 0; i < 2; i++) gA[i] = *(const bf16x8*)(aSrc[i] + koff_); \
        _Pragma("unroll")                                                  \
        for (int j = 0; j < 5; j++) gB[j] = *(const bf16x8*)(bSrc[j] + (kk)); \
    } while (0)
#define CSTAGE_WRITE() do {                                                \
        _Pragma("unroll")                                                  \
        for (int i = 0; i < 2; i++) *(bf16x8*)aDst[i] = gA[i];             \
        _Pragma("unroll")                                                  \
        for (int j = 0; j < 5; j++) *(bf16x8*)bDst[j] = gB[j];             \
    } while (0)

    CSTAGE_LOAD(0);
    CSTAGE_WRITE();
    __syncthreads();

    for (int ks = 0; ks < 16; ks++) {
        if (ks < 15) CSTAGE_LOAD((ks + 1) * 32);
        bf16x8 fa[2][2], fb[2][5];
#pragma unroll
        for (int t = 0; t < 2; t++) {
            int ar = wm * 32 + t * 16 + lr;
            fa[0][t] = *(const bf16x8*)&sAm[0][ar][lk];
            fa[1][t] = *(const bf16x8*)&sAm[1][ar][lk];
        }
#pragma unroll
        for (int gt = 0; gt < 5; gt++) {
            int br = gt * 32 + wn * 16 + lr;
            fb[0][gt] = *(const bf16x8*)&sBm[0][br][lk];
            fb[1][gt] = *(const bf16x8*)&sBm[1][br][lk];
        }
#pragma unroll
        for (int gt = 0; gt < 5; gt++)
#pragma unroll
            for (int t = 0; t < 2; t++) {
                acc[t][gt] = __builtin_amdgcn_mfma_f32_16x16x32_bf16(fa[0][t], fb[0][gt], acc[t][gt], 0, 0, 0);
                acc[t][gt] = __builtin_amdgcn_mfma_f32_16x16x32_bf16(fa[0][t], fb[1][gt], acc[t][gt], 0, 0, 0);
                acc[t][gt] = __builtin_amdgcn_mfma_f32_16x16x32_bf16(fa[1][t], fb[0][gt], acc[t][gt], 0, 0, 0);
            }
        __syncthreads();
        if (ks < 15) {
            CSTAGE_WRITE();
            __syncthreads();
        }
    }
#undef CSTAGE_LOAD
#undef CSTAGE_WRITE

#pragma unroll
    for (int t = 0; t < 2; t++)
#pragma unroll
        for (int r = 0; r < 4; r++) {
            int lrow = wm * 32 + t * 16 + ((l >> 4) << 2) + r;
            int m = r0 + lrow;
            size_t sb = (size_t)rb[lrow];
            int c = cbw + lr;
            float cl = scoef[lrow][0], cr = scoef[lrow][1], sel = scoef[lrow][2];
            float h_l = bf2f(sh[sb + c])       + bf2f(sl[sb + c]);
            float c_l = bf2f(sh[sb + 256 + c]) + bf2f(sl[sb + 256 + c]);
            float h_r = bf2f(sh[sb + 512 + c]) + bf2f(sl[sb + 512 + c]);
            float c_r = bf2f(sh[sb + 768 + c]) + bf2f(sl[sb + 768 + c]);
            float gi  = acc[t][0][r] + bias[0];
            float gfl = acc[t][1][r] + bias[1];
            float gfr = acc[t][2][r] + bias[2];
            float gu  = acc[t][3][r] + bias[3];
            float go  = acc[t][4][r] + bias[4];
            float cn = sigf(gfl) * c_l + sigf(gfr) * c_r + sigf(gi) * tanhf(gu);
            float hn = sigf(go) * tanhf(cn);
            float oh = cl * h_l + cr * h_r + sel * hn;
            float oc = cl * c_l + cr * c_r + sel * cn;
            size_t ob = (size_t)m * 512 + c;
            ushort hh = bf16r(oh);
            dh[ob] = hh;
            dl[ob] = bf16r(oh - bf2f(hh));
            ushort hc = bf16r(oc);
            dh[ob + 256] = hc;
            dl[ob + 256] = bf16r(oc - bf2f(hc));
            if (N == 1) {                       // final layer: fp32 root for the MLP head
                root[ob] = oh;
                root[ob + 256] = oc;
            }
        }
}

// ---------------- generic small fp32 GEMM with optional ReLU (final MLP) ----------------
template <int ACT>
__global__ __launch_bounds__(256) void k_gemm(const float* __restrict__ A,
                                              const float* __restrict__ W,
                                              const float* __restrict__ bias,
                                              float* __restrict__ C,
                                              int M, int K, int Nc) {
    __shared__ float Xs[32][36];
    __shared__ float Ws[32][64];
    int tid = threadIdx.x;
    int r0 = blockIdx.x * 32, c0 = blockIdx.y * 64;
    int ct = tid & 15, rt = tid >> 4;
    float acc[2][4];
#pragma unroll
    for (int r = 0; r < 2; r++)
#pragma unroll
        for (int q = 0; q < 4; q++) {
            int c = c0 + ct * 4 + q;
            acc[r][q] = (c < Nc) ? bias[c] : 0.f;
        }
    for (int kk = 0; kk < K; kk += 32) {
        __syncthreads();
        {
            int m = tid >> 3, k4 = (tid & 7) << 2;
            float4 v = {0.f, 0.f, 0.f, 0.f};
            if (r0 + m < M) v = *(const float4*)(A + (size_t)(r0 + m) * K + kk + k4);
            Xs[k4 + 0][m] = v.x; Xs[k4 + 1][m] = v.y; Xs[k4 + 2][m] = v.z; Xs[k4 + 3][m] = v.w;
        }
#pragma unroll
        for (int i = 0; i < 2; i++) {
            int idx = tid + i * 256;
            int k = idx >> 4, c4 = (idx & 15) << 2;
            int c = c0 + c4;
            float4 v = {0.f, 0.f, 0.f, 0.f};
            if (c + 3 < Nc) {
                v = *(const float4*)(W + (size_t)(kk + k) * Nc + c);
            } else {
                float tmp[4] = {0.f, 0.f, 0.f, 0.f};
                for (int j = 0; j < 4; j++)
                    if (c + j < Nc) tmp[j] = W[(size_t)(kk + k) * Nc + c + j];
                v = *(float4*)tmp;
            }
            *(float4*)&Ws[k][c4] = v;
        }
        __syncthreads();
#pragma unroll
        for (int k = 0; k < 32; k++) {
            float x0 = Xs[k][rt * 2], x1 = Xs[k][rt * 2 + 1];
            float wv[4];
            *(float4*)wv = *(const float4*)&Ws[k][ct * 4];
#pragma unroll
            for (int q = 0; q < 4; q++) { acc[0][q] += x0 * wv[q]; acc[1][q] += x1 * wv[q]; }
        }
    }
#pragma unroll
    for (int r = 0; r < 2; r++) {
        int g = r0 + rt * 2 + r;
        if (g >= M) continue;
#pragma unroll
        for (int q = 0; q < 4; q++) {
            int c = c0 + ct * 4 + q;
            if (c >= Nc) continue;
            float v = acc[r][q];
            if (ACT == 1) v = fmaxf(v, 0.f);
            C[(size_t)g * Nc + c] = v;
        }
    }
}

extern "C" void kernel_launch(void* const* d_in, const int* in_sizes, int n_in,
                              void* d_out, int out_size, void* d_ws, size_t ws_size,
                              hipStream_t stream) {
    const int*   sent     = (const int*)d_in[0];
    // d_in[1] transitions: unused by reference
    const float* emb      = (const float*)d_in[2];
    const float* comp_W   = (const float*)d_in[3];
    const float* comp_b   = (const float*)d_in[4];
    const float* sel_W1   = (const float*)d_in[5];
    const float* sel_b1   = (const float*)d_in[6];
    const float* sel_W2   = (const float*)d_in[7];
    const float* sel_b2   = (const float*)d_in[8];
    const float* mlp_W0   = (const float*)d_in[9];
    const float* mlp_b0   = (const float*)d_in[10];
    const float* mlp_W1   = (const float*)d_in[11];
    const float* mlp_b1   = (const float*)d_in[12];
    const float* mlp_Wout = (const float*)d_in[13];
    const float* mlp_bout = (const float*)d_in[14];
    float* outp = (float*)d_out;

    char* p = (char*)d_ws;
    ushort* sh0  = (ushort*)p; p += (size_t)B_ * S_ * D_ * 2;
    ushort* sl0  = (ushort*)p; p += (size_t)B_ * S_ * D_ * 2;
    ushort* sh1  = (ushort*)p; p += (size_t)B_ * S_ * D_ * 2;
    ushort* sl1  = (ushort*)p; p += (size_t)B_ * S_ * D_ * 2;
    ushort* wth  = (ushort*)p; p += (size_t)1280 * 512 * 2;
    ushort* wtl  = (ushort*)p; p += (size_t)1280 * 512 * 2;
    ushort* w1th = (ushort*)p; p += (size_t)128 * 1024 * 2;
    ushort* w1tl = (ushort*)p; p += (size_t)128 * 1024 * 2;
    float*  logits = (float*)p; p += (size_t)B_ * 63 * 4;
    float*  root = (float*)p;  p += (size_t)B_ * D_ * 4;
    float*  h1   = (float*)p;  p += (size_t)B_ * MLPD_ * 4;
    float*  h2   = (float*)p;  p += (size_t)B_ * MLPD_ * 4;

    k_embed<<<dim3(4096), dim3(256), 0, stream>>>(sent, emb, sh0, sl0);
    k_tsplit<<<dim3(20, 8), dim3(256), 0, stream>>>(comp_W, wth, wtl, 512, 1280);
    k_tsplit<<<dim3(2, 16), dim3(256), 0, stream>>>(sel_W1, w1th, w1tl, 1024, 128);

    ushort* shs = sh0; ushort* sls = sl0;
    ushort* shd = sh1; ushort* sld = sl1;
    for (int L = S_; L >= 2; --L) {
        int N = L - 1;
        int M = B_ * N;
        int cdiv = (1048576 + N - 1) / N;
        k_sellogit<<<dim3(M / 64), dim3(256), 0, stream>>>(shs, sls, w1th, w1tl, sel_b1,
                                                           sel_W2, sel_b2, logits, N, M, cdiv);
        k_compose<<<dim3(8 * (M / 64)), dim3(256), 0, stream>>>(shs, sls, wth, wtl, comp_b, logits,
                                                                shd, sld, root, N, M, cdiv);
        ushort* th = shs; shs = shd; shd = th;
        ushort* tl = sls; sls = sld; sld = tl;
    }

    k_gemm<1><<<dim3(4, 16), dim3(256), 0, stream>>>(root, mlp_W0, mlp_b0, h1, B_, 512, MLPD_);
    k_gemm<1><<<dim3(4, 16), dim3(256), 0, stream>>>(h1, mlp_W1, mlp_b1, h2, B_, 1024, MLPD_);
    k_gemm<0><<<dim3(4, 1), dim3(256), 0, stream>>>(h2, mlp_Wout, mlp_bout, outp, B_, 1024, CLS_);
}

// Round 11
// 3691.418 us; speedup vs baseline: 1.1229x; 1.1229x over previous
//
#include <hip/hip_runtime.h>
#include <hip/hip_bf16.h>
#include <math.h>

#define B_ 128
#define S_ 64
#define D_ 512
#define H_ 256
#define SEL_ 128
#define MLPD_ 1024
#define CLS_ 3

typedef __attribute__((ext_vector_type(8))) short bf16x8;
typedef __attribute__((ext_vector_type(4))) float f32x4;

__device__ __forceinline__ float sigf(float x) { return 1.f / (1.f + expf(-x)); }

// fp32 -> bf16 round-to-nearest-even (bit trick; no inf/nan in this workload)
__device__ __forceinline__ ushort bf16r(float x) {
    uint u = __float_as_uint(x);
    return (ushort)((u + 0x7fffu + ((u >> 16) & 1u)) >> 16);
}
__device__ __forceinline__ float bf2f(ushort h) { return __uint_as_float(((uint)h) << 16); }

// XCD-chunk swizzle (T1, m204 bijective): XCD k = bid%8 owns a contiguous chunk of w.
__device__ __forceinline__ int xcd_chunk(int bid, int nb) {
    int q = nb >> 3, r = nb & 7;
    int xcd = bid & 7, j = bid >> 3;
    return (xcd < r ? xcd * (q + 1) : r * (q + 1) + (xcd - r) * q) + j;
}

// ---------------- embedding gather + bf16 hi/lo split (state := hi+lo) ----------------
__global__ __launch_bounds__(256) void k_embed(const int* __restrict__ sent,
                                               const float* __restrict__ emb,
                                               ushort* __restrict__ oh,
                                               ushort* __restrict__ ol) {
    int idx = blockIdx.x * 256 + threadIdx.x;      // B*S*D/4 float4 slots
    int row = idx >> 7;
    int k4 = (idx & 127) << 2;
    int tok = sent[row];
    float4 v = *(const float4*)(emb + (size_t)tok * D_ + k4);
    ushort4 h, l;
    h.x = bf16r(v.x); l.x = bf16r(v.x - bf2f(h.x));
    h.y = bf16r(v.y); l.y = bf16r(v.y - bf2f(h.y));
    h.z = bf16r(v.z); l.z = bf16r(v.z - bf2f(h.z));
    h.w = bf16r(v.w); l.w = bf16r(v.w - bf2f(h.w));
    *(ushort4*)(oh + (size_t)row * D_ + k4) = h;
    *(ushort4*)(ol + (size_t)row * D_ + k4) = l;
}

// ---------------- transpose + split: dst[n][k] = src[k][n], K,N multiples of 64 ----------------
__global__ __launch_bounds__(256) void k_tsplit(const float* __restrict__ src,
                                                ushort* __restrict__ dh,
                                                ushort* __restrict__ dl,
                                                int K, int N) {
    __shared__ float t[64][65];
    int n0 = blockIdx.x * 64, k0 = blockIdx.y * 64;
    int tx = threadIdx.x & 63, ty = threadIdx.x >> 6;
    for (int i = ty; i < 64; i += 4)
        t[i][tx] = src[(size_t)(k0 + i) * N + n0 + tx];
    __syncthreads();
    for (int i = ty; i < 64; i += 4) {
        float v = t[tx][i];
        ushort h = bf16r(v);
        size_t o = (size_t)(n0 + i) * K + k0 + tx;
        dh[o] = h;
        dl[o] = bf16r(v - bf2f(h));
    }
}

// ---------------- selection hidden + logits, fused; 32 rows x 128 cols per block ----------------
// grid M/32 (252 blocks at the largest layer). LDS-staged bf16x2 MFMA, K=1024, BK=32.
// Epilogue: logits[g] = sum_c tanh(acc+b1[c])*W2[c] + b2 (16-lane shuffle + LDS combine).
__global__ __launch_bounds__(256) void k_sellogit(const ushort* __restrict__ sh,
                                                  const ushort* __restrict__ sl,
                                                  const ushort* __restrict__ w1h,
                                                  const ushort* __restrict__ w1l,
                                                  const float* __restrict__ b1,
                                                  const float* __restrict__ W2,
                                                  const float* __restrict__ b2,
                                                  float* __restrict__ logits,
                                                  int N, int M, int cdiv) {
    __shared__ __align__(16) ushort sAm[2][32][40];
    __shared__ __align__(16) ushort sBm[2][128][40];
    __shared__ int rb[32];
    __shared__ float lpart[2][32];
    int w = xcd_chunk(blockIdx.x, gridDim.x);
    int r0 = w * 32;
    int tid = threadIdx.x, l = tid & 63, wid = tid >> 6;
    int rt2 = wid & 1, ch = wid >> 1;          // row 16-tile, col half (64)
    int lr = l & 15, lk = (l >> 4) << 3;

    if (tid < 32) {
        int g = r0 + tid;
        int q = (int)(((long long)g * cdiv) >> 20);      // g / N
        rb[tid] = (g + q) * 512;
    }
    __syncthreads();

    float bias[4], w2v[4];
#pragma unroll
    for (int tj = 0; tj < 4; tj++) {
        int c = ch * 64 + tj * 16 + lr;
        bias[tj] = b1[c];
        w2v[tj] = W2[c];
    }

    // A: 2 planes x 32 rows x 4 segs = 256 loads (1/thread)
    int pA = tid >> 7, remA = tid & 127;
    int rA = remA >> 2, sA = remA & 3;
    const ushort* aSrc = (pA ? sl : sh) + rb[rA] + sA * 8;
    ushort* aDst = &sAm[pA][rA][sA * 8];
    // B: 2 planes x 128 rows x 4 segs = 1024 loads (4/thread)
    const ushort* bSrc[4]; ushort* bDst[4];
#pragma unroll
    for (int j = 0; j < 4; j++) {
        int idx = tid + j * 256;
        int p = (idx >= 512) ? 1 : 0;
        int rem = idx - p * 512;
        int br = rem >> 2, s = rem & 3;
        bSrc[j] = (p ? w1l : w1h) + br * 1024 + s * 8;
        bDst[j] = &sBm[p][br][s * 8];
    }

    f32x4 z = {0.f, 0.f, 0.f, 0.f};
    f32x4 acc[4] = {z, z, z, z};
    bf16x8 gA, gB[4];

#define SSTAGE_LOAD(kk) do {                                               \
        gA = *(const bf16x8*)(aSrc + (kk));                                \
        _Pragma("unroll")                                                  \
        for (int j = 0; j < 4; j++) gB[j] = *(const bf16x8*)(bSrc[j] + (kk)); \
    } while (0)
#define SSTAGE_WRITE() do {                                                \
        *(bf16x8*)aDst = gA;                                               \
        _Pragma("unroll")                                                  \
        for (int j = 0; j < 4; j++) *(bf16x8*)bDst[j] = gB[j];             \
    } while (0)

    SSTAGE_LOAD(0);
    SSTAGE_WRITE();
    __syncthreads();

    for (int ks = 0; ks < 32; ks++) {
        if (ks < 31) SSTAGE_LOAD((ks + 1) * 32);
        bf16x8 fa[2], fb[2][4];
        {
            int ar = rt2 * 16 + lr;
            fa[0] = *(const bf16x8*)&sAm[0][ar][lk];
            fa[1] = *(const bf16x8*)&sAm[1][ar][lk];
        }
#pragma unroll
        for (int tj = 0; tj < 4; tj++) {
            int bc = ch * 64 + tj * 16 + lr;
            fb[0][tj] = *(const bf16x8*)&sBm[0][bc][lk];
            fb[1][tj] = *(const bf16x8*)&sBm[1][bc][lk];
        }
#pragma unroll
        for (int tj = 0; tj < 4; tj++) {
            acc[tj] = __builtin_amdgcn_mfma_f32_16x16x32_bf16(fa[0], fb[0][tj], acc[tj], 0, 0, 0);
            acc[tj] = __builtin_amdgcn_mfma_f32_16x16x32_bf16(fa[0], fb[1][tj], acc[tj], 0, 0, 0);
            acc[tj] = __builtin_amdgcn_mfma_f32_16x16x32_bf16(fa[1], fb[0][tj], acc[tj], 0, 0, 0);
        }
        __syncthreads();
        if (ks < 31) {
            SSTAGE_WRITE();
            __syncthreads();
        }
    }
#undef SSTAGE_LOAD
#undef SSTAGE_WRITE

    float part[4];
#pragma unroll
    for (int r = 0; r < 4; r++) {
        float s = 0.f;
#pragma unroll
        for (int tj = 0; tj < 4; tj++)
            s += tanhf(acc[tj][r] + bias[tj]) * w2v[tj];
        part[r] = s;
    }
#pragma unroll
    for (int off = 1; off < 16; off <<= 1)
#pragma unroll
        for (int r = 0; r < 4; r++)
            part[r] += __shfl_xor(part[r], off);
    if ((l & 15) == 0) {
#pragma unroll
        for (int r = 0; r < 4; r++)
            lpart[ch][rt2 * 16 + ((l >> 4) << 2) + r] = part[r];
    }
    __syncthreads();
    if (tid < 32)
        logits[r0 + tid] = lpart[0][tid] + lpart[1][tid] + b2[0];
}

// ---------------- fused softmax/cumsum + gates GEMM + treeLSTM + combine ----------------
__global__ __launch_bounds__(256) void k_compose(const ushort* __restrict__ sh,
                                                 const ushort* __restrict__ sl,
                                                 const ushort* __restrict__ wth,
                                                 const ushort* __restrict__ wtl,
                                                 const float* __restrict__ cbias,
                                                 const float* __restrict__ logits,
                                                 ushort* __restrict__ dh,
                                                 ushort* __restrict__ dl,
                                                 ushort* __restrict__ rh,
                                                 ushort* __restrict__ rl,
                                                 int N, int M, int cdiv) {
    __shared__ __align__(16) ushort sAm[2][64][40];
    __shared__ __align__(16) ushort sBm[2][160][40];
    __shared__ int rb[64];
    __shared__ float slog[192];
    __shared__ float scoef[64][3];
    int w = xcd_chunk(blockIdx.x, gridDim.x);
    int cx = w & 7, ry = w >> 3;
    int tid = threadIdx.x, l = tid & 63, wid = tid >> 6;
    int wm = wid >> 1, wn = wid & 1;
    int r0 = ry * 64;
    int cb_blk = cx * 32;
    int cbw = cb_blk + wn * 16;
    int lr = l & 15, lk = (l >> 4) << 3;

    int blo = (int)(((long long)r0 * cdiv) >> 20);            // r0 / N
    int bhi = (int)(((long long)(r0 + 63) * cdiv) >> 20);     // (r0+63) / N
    int cnt = (bhi - blo + 1) * N;
    if (tid < 64) {
        int g = r0 + tid;
        int q = (int)(((long long)g * cdiv) >> 20);
        rb[tid] = (g + q) * 512;
    }
    if (tid < cnt) slog[tid] = logits[blo * N + tid];
    __syncthreads();

    if (tid < 64) {
        int g = r0 + tid;
        int b = (int)(((long long)g * cdiv) >> 20);
        int j = g - b * N;
        int o = (b - blo) * N;
        float mx = -1e30f;
        for (int k = 0; k < N; k++) mx = fmaxf(mx, slog[o + k]);
        float tot = 0.f, cs = 0.f, pj = 0.f;
        for (int k = 0; k < N; k++) {
            float e = expf(slog[o + k] - mx);
            tot += e;
            if (k <= j) cs += e;
            if (k == j) pj = e;
        }
        float inv = 1.f / tot;
        scoef[tid][0] = (tot - cs) * inv;   // copy_left
        scoef[tid][1] = (cs - pj) * inv;    // copy_right
        scoef[tid][2] = pj * inv;           // select
    }

    float bias[5];
#pragma unroll
    for (int gt = 0; gt < 5; gt++) bias[gt] = cbias[gt * 256 + cbw + lr];

    const ushort* aSrc[2]; ushort* aDst[2];
#pragma unroll
    for (int i = 0; i < 2; i++) {
        int idx = tid + i * 256;
        int p = idx >> 8, rem = idx & 255;
        int r = rem >> 2, s = rem & 3;
        aSrc[i] = (p ? sl : sh) + rb[r] + s * 8;
        aDst[i] = &sAm[p][r][s * 8];
    }
    const ushort* bSrc[5]; ushort* bDst[5];
#pragma unroll
    for (int j = 0; j < 5; j++) {
        int idx = tid + j * 256;
        int p = (idx >= 640) ? 1 : 0;
        int rem = idx - p * 640;
        int br = rem >> 2, s = rem & 3;
        int col = (br >> 5) * 256 + cb_blk + (br & 31);
        bSrc[j] = (p ? wtl : wth) + col * 512 + s * 8;
        bDst[j] = &sBm[p][br][s * 8];
    }

    f32x4 z = {0.f, 0.f, 0.f, 0.f};
    f32x4 acc[2][5] = {{z, z, z, z, z}, {z, z, z, z, z}};
    bf16x8 gA[2], gB[5];

#define CSTAGE_LOAD(kk) do {                                               \
        int koff_ = ((kk) < 256) ? (kk) : (kk) + 256;                      \
        _Pragma("unroll")                                                  \
        for (int i = 0; i < 2; i++) gA[i] = *(const bf16x8*)(aSrc[i] + koff_); \
        _Pragma("unroll")                                                  \
        for (int j = 0; j < 5; j++) gB[j] = *(const bf16x8*)(bSrc[j] + (kk)); \
    } while (0)
#define CSTAGE_WRITE() do {                                                \
        _Pragma("unroll")                                                  \
        for (int i = 0; i < 2; i++) *(bf16x8*)aDst[i] = gA[i];             \
        _Pragma("unroll")                                                  \
        for (int j = 0; j < 5; j++) *(bf16x8*)bDst[j] = gB[j];             \
    } while (0)

    CSTAGE_LOAD(0);
    CSTAGE_WRITE();
    __syncthreads();

    for (int ks = 0; ks < 16; ks++) {
        if (ks < 15) CSTAGE_LOAD((ks + 1) * 32);
        bf16x8 fa[2][2], fb[2][5];
#pragma unroll
        for (int t = 0; t < 2; t++) {
            int ar = wm * 32 + t * 16 + lr;
            fa[0][t] = *(const bf16x8*)&sAm[0][ar][lk];
            fa[1][t] = *(const bf16x8*)&sAm[1][ar][lk];
        }
#pragma unroll
        for (int gt = 0; gt < 5; gt++) {
            int br = gt * 32 + wn * 16 + lr;
            fb[0][gt] = *(const bf16x8*)&sBm[0][br][lk];
            fb[1][gt] = *(const bf16x8*)&sBm[1][br][lk];
        }
#pragma unroll
        for (int gt = 0; gt < 5; gt++)
#pragma unroll
            for (int t = 0; t < 2; t++) {
                acc[t][gt] = __builtin_amdgcn_mfma_f32_16x16x32_bf16(fa[0][t], fb[0][gt], acc[t][gt], 0, 0, 0);
                acc[t][gt] = __builtin_amdgcn_mfma_f32_16x16x32_bf16(fa[0][t], fb[1][gt], acc[t][gt], 0, 0, 0);
                acc[t][gt] = __builtin_amdgcn_mfma_f32_16x16x32_bf16(fa[1][t], fb[0][gt], acc[t][gt], 0, 0, 0);
            }
        __syncthreads();
        if (ks < 15) {
            CSTAGE_WRITE();
            __syncthreads();
        }
    }
#undef CSTAGE_LOAD
#undef CSTAGE_WRITE

#pragma unroll
    for (int t = 0; t < 2; t++)
#pragma unroll
        for (int r = 0; r < 4; r++) {
            int lrow = wm * 32 + t * 16 + ((l >> 4) << 2) + r;
            int m = r0 + lrow;
            size_t sb = (size_t)rb[lrow];
            int c = cbw + lr;
            float cl = scoef[lrow][0], cr = scoef[lrow][1], sel = scoef[lrow][2];
            float h_l = bf2f(sh[sb + c])       + bf2f(sl[sb + c]);
            float c_l = bf2f(sh[sb + 256 + c]) + bf2f(sl[sb + 256 + c]);
            float h_r = bf2f(sh[sb + 512 + c]) + bf2f(sl[sb + 512 + c]);
            float c_r = bf2f(sh[sb + 768 + c]) + bf2f(sl[sb + 768 + c]);
            float gi  = acc[t][0][r] + bias[0];
            float gfl = acc[t][1][r] + bias[1];
            float gfr = acc[t][2][r] + bias[2];
            float gu  = acc[t][3][r] + bias[3];
            float go  = acc[t][4][r] + bias[4];
            float cn = sigf(gfl) * c_l + sigf(gfr) * c_r + sigf(gi) * tanhf(gu);
            float hn = sigf(go) * tanhf(cn);
            float oh = cl * h_l + cr * h_r + sel * hn;
            float oc = cl * c_l + cr * c_r + sel * cn;
            size_t ob = (size_t)m * 512 + c;
            ushort hh = bf16r(oh);
            ushort hl = bf16r(oh - bf2f(hh));
            ushort hc = bf16r(oc);
            ushort lc = bf16r(oc - bf2f(hc));
            dh[ob] = hh;       dl[ob] = hl;
            dh[ob + 256] = hc; dl[ob + 256] = lc;
            if (N == 1) {      // final layer: dense hi/lo root planes for the MLP head
                rh[ob] = hh;       rl[ob] = hl;
                rh[ob + 256] = hc; rl[ob + 256] = lc;
            }
        }
}

// ---------------- MLP layer via MFMA bf16x2: 32 rows x 128 cols per block ----------------
// grid (M/32, Nc/128). ACT: relu. SPLITOUT: write hi/lo planes, else fp32.
template <int ACT, int SPLITOUT>
__global__ __launch_bounds__(256) void k_mlp(const ushort* __restrict__ Ah,
                                             const ushort* __restrict__ Al,
                                             const ushort* __restrict__ Bh,
                                             const ushort* __restrict__ Bl,
                                             const float* __restrict__ bias,
                                             ushort* __restrict__ oh,
                                             ushort* __restrict__ ol,
                                             float* __restrict__ of,
                                             int K, int Nc) {
    __shared__ __align__(16) ushort sAm[2][32][40];
    __shared__ __align__(16) ushort sBm[2][128][40];
    int r0 = blockIdx.x * 32, cb = blockIdx.y * 128;
    int tid = threadIdx.x, l = tid & 63, wid = tid >> 6;
    int rt2 = wid & 1, ch = wid >> 1;
    int lr = l & 15, lk = (l >> 4) << 3;

    float bias4[4];
#pragma unroll
    for (int tj = 0; tj < 4; tj++) bias4[tj] = bias[cb + ch * 64 + tj * 16 + lr];

    int pA = tid >> 7, remA = tid & 127;
    int rA = remA >> 2, sA = remA & 3;
    const ushort* aSrc = (pA ? Al : Ah) + (size_t)(r0 + rA) * K + sA * 8;
    ushort* aDst = &sAm[pA][rA][sA * 8];
    const ushort* bSrc[4]; ushort* bDst[4];
#pragma unroll
    for (int j = 0; j < 4; j++) {
        int idx = tid + j * 256;
        int p = (idx >= 512) ? 1 : 0;
        int rem = idx - p * 512;
        int br = rem >> 2, s = rem & 3;
        bSrc[j] = (p ? Bl : Bh) + (size_t)(cb + br) * K + s * 8;
        bDst[j] = &sBm[p][br][s * 8];
    }

    f32x4 z = {0.f, 0.f, 0.f, 0.f};
    f32x4 acc[4] = {z, z, z, z};
    bf16x8 gA, gB[4];

#define MSTAGE_LOAD(kk) do {                                               \
        gA = *(const bf16x8*)(aSrc + (kk));                                \
        _Pragma("unroll")                                                  \
        for (int j = 0; j < 4; j++) gB[j] = *(const bf16x8*)(bSrc[j] + (kk)); \
    } while (0)
#define MSTAGE_WRITE() do {                                                \
        *(bf16x8*)aDst = gA;                                               \
        _Pragma("unroll")                                                  \
        for (int j = 0; j < 4; j++) *(bf16x8*)bDst[j] = gB[j];             \
    } while (0)

    MSTAGE_LOAD(0);
    MSTAGE_WRITE();
    __syncthreads();

    int nks = K >> 5;
    for (int ks = 0; ks < nks; ks++) {
        if (ks < nks - 1) MSTAGE_LOAD((ks + 1) * 32);
        bf16x8 fa[2], fb[2][4];
        {
            int ar = rt2 * 16 + lr;
            fa[0] = *(const bf16x8*)&sAm[0][ar][lk];
            fa[1] = *(const bf16x8*)&sAm[1][ar][lk];
        }
#pragma unroll
        for (int tj = 0; tj < 4; tj++) {
            int bc = ch * 64 + tj * 16 + lr;
            fb[0][tj] = *(const bf16x8*)&sBm[0][bc][lk];
            fb[1][tj] = *(const bf16x8*)&sBm[1][bc][lk];
        }
#pragma unroll
        for (int tj = 0; tj < 4; tj++) {
            acc[tj] = __builtin_amdgcn_mfma_f32_16x16x32_bf16(fa[0], fb[0][tj], acc[tj], 0, 0, 0);
            acc[tj] = __builtin_amdgcn_mfma_f32_16x16x32_bf16(fa[0], fb[1][tj], acc[tj], 0, 0, 0);
            acc[tj] = __builtin_amdgcn_mfma_f32_16x16x32_bf16(fa[1], fb[0][tj], acc[tj], 0, 0, 0);
        }
        __syncthreads();
        if (ks < nks - 1) {
            MSTAGE_WRITE();
            __syncthreads();
        }
    }
#undef MSTAGE_LOAD
#undef MSTAGE_WRITE

#pragma unroll
    for (int tj = 0; tj < 4; tj++)
#pragma unroll
        for (int r = 0; r < 4; r++) {
            int grow = r0 + rt2 * 16 + ((l >> 4) << 2) + r;
            int gcol = cb + ch * 64 + tj * 16 + lr;
            float v = acc[tj][r] + bias4[tj];
            if (ACT == 1) v = fmaxf(v, 0.f);
            if (SPLITOUT) {
                ushort h = bf16r(v);
                oh[(size_t)grow * Nc + gcol] = h;
                ol[(size_t)grow * Nc + gcol] = bf16r(v - bf2f(h));
            } else {
                of[(size_t)grow * Nc + gcol] = v;
            }
        }
}

// ---------------- final classifier: out[row][c] = h2[row] . Wout[:,c] + bout[c] ----------------
__global__ __launch_bounds__(64) void k_cls(const float* __restrict__ h2,
                                            const float* __restrict__ Wout,
                                            const float* __restrict__ bout,
                                            float* __restrict__ out) {
    int row = blockIdx.x, lane = threadIdx.x;
    float s0 = 0.f, s1 = 0.f, s2 = 0.f;
    for (int k = lane; k < 1024; k += 64) {
        float v = h2[(size_t)row * 1024 + k];
        s0 += v * Wout[k * 3 + 0];
        s1 += v * Wout[k * 3 + 1];
        s2 += v * Wout[k * 3 + 2];
    }
#pragma unroll
    for (int o = 32; o >= 1; o >>= 1) {
        s0 += __shfl_down(s0, o);
        s1 += __shfl_down(s1, o);
        s2 += __shfl_down(s2, o);
    }
    if (lane == 0) {
        out[row * 3 + 0] = s0 + bout[0];
        out[row * 3 + 1] = s1 + bout[1];
        out[row * 3 + 2] = s2 + bout[2];
    }
}

extern "C" void kernel_launch(void* const* d_in, const int* in_sizes, int n_in,
                              void* d_out, int out_size, void* d_ws, size_t ws_size,
                              hipStream_t stream) {
    const int*   sent     = (const int*)d_in[0];
    // d_in[1] transitions: unused by reference
    const float* emb      = (const float*)d_in[2];
    const float* comp_W   = (const float*)d_in[3];
    const float* comp_b   = (const float*)d_in[4];
    const float* sel_W1   = (const float*)d_in[5];
    const float* sel_b1   = (const float*)d_in[6];
    const float* sel_W2   = (const float*)d_in[7];
    const float* sel_b2   = (const float*)d_in[8];
    const float* mlp_W0   = (const float*)d_in[9];
    const float* mlp_b0   = (const float*)d_in[10];
    const float* mlp_W1   = (const float*)d_in[11];
    const float* mlp_b1   = (const float*)d_in[12];
    const float* mlp_Wout = (const float*)d_in[13];
    const float* mlp_bout = (const float*)d_in[14];
    float* outp = (float*)d_out;

    char* p = (char*)d_ws;
    ushort* sh0  = (ushort*)p; p += (size_t)B_ * S_ * D_ * 2;
    ushort* sl0  = (ushort*)p; p += (size_t)B_ * S_ * D_ * 2;
    ushort* sh1  = (ushort*)p; p += (size_t)B_ * S_ * D_ * 2;
    ushort* sl1  = (ushort*)p; p += (size_t)B_ * S_ * D_ * 2;
    ushort* wth  = (ushort*)p; p += (size_t)1280 * 512 * 2;
    ushort* wtl  = (ushort*)p; p += (size_t)1280 * 512 * 2;
    ushort* w1th = (ushort*)p; p += (size_t)128 * 1024 * 2;
    ushort* w1tl = (ushort*)p; p += (size_t)128 * 1024 * 2;
    ushort* w0th = (ushort*)p; p += (size_t)1024 * 512 * 2;
    ushort* w0tl = (ushort*)p; p += (size_t)1024 * 512 * 2;
    ushort* w1mh = (ushort*)p; p += (size_t)1024 * 1024 * 2;
    ushort* w1ml = (ushort*)p; p += (size_t)1024 * 1024 * 2;
    float*  logits = (float*)p; p += (size_t)B_ * 63 * 4;
    ushort* rh   = (ushort*)p; p += (size_t)B_ * D_ * 2;
    ushort* rl   = (ushort*)p; p += (size_t)B_ * D_ * 2;
    ushort* h1h  = (ushort*)p; p += (size_t)B_ * MLPD_ * 2;
    ushort* h1l  = (ushort*)p; p += (size_t)B_ * MLPD_ * 2;
    float*  h2   = (float*)p;  p += (size_t)B_ * MLPD_ * 4;

    k_embed<<<dim3(4096), dim3(256), 0, stream>>>(sent, emb, sh0, sl0);
    k_tsplit<<<dim3(20, 8), dim3(256), 0, stream>>>(comp_W, wth, wtl, 512, 1280);
    k_tsplit<<<dim3(2, 16), dim3(256), 0, stream>>>(sel_W1, w1th, w1tl, 1024, 128);
    k_tsplit<<<dim3(16, 8), dim3(256), 0, stream>>>(mlp_W0, w0th, w0tl, 512, 1024);
    k_tsplit<<<dim3(16, 16), dim3(256), 0, stream>>>(mlp_W1, w1mh, w1ml, 1024, 1024);

    ushort* shs = sh0; ushort* sls = sl0;
    ushort* shd = sh1; ushort* sld = sl1;
    for (int L = S_; L >= 2; --L) {
        int N = L - 1;
        int M = B_ * N;
        int cdiv = (1048576 + N - 1) / N;
        k_sellogit<<<dim3(M / 32), dim3(256), 0, stream>>>(shs, sls, w1th, w1tl, sel_b1,
                                                           sel_W2, sel_b2, logits, N, M, cdiv);
        k_compose<<<dim3(8 * (M / 64)), dim3(256), 0, stream>>>(shs, sls, wth, wtl, comp_b, logits,
                                                                shd, sld, rh, rl, N, M, cdiv);
        ushort* th = shs; shs = shd; shd = th;
        ushort* tl = sls; sls = sld; sld = tl;
    }

    k_mlp<1, 1><<<dim3(4, 8), dim3(256), 0, stream>>>(rh, rl, w0th, w0tl, mlp_b0,
                                                      h1h, h1l, nullptr, 512, MLPD_);
    k_mlp<1, 0><<<dim3(4, 8), dim3(256), 0, stream>>>(h1h, h1l, w1mh, w1ml, mlp_b1,
                                                      nullptr, nullptr, h2, 1024, MLPD_);
    k_cls<<<dim3(B_), dim3(64), 0, stream>>>(h2, mlp_Wout, mlp_bout, outp);
}

// Round 12
// 3685.591 us; speedup vs baseline: 1.1247x; 1.0016x over previous
//
#include <hip/hip_runtime.h>
#include <hip/hip_bf16.h>
#include <math.h>

#define B_ 128
#define S_ 64
#define D_ 512
#define H_ 256
#define SEL_ 128
#define MLPD_ 1024
#define CLS_ 3

typedef __attribute__((ext_vector_type(8))) short bf16x8;
typedef __attribute__((ext_vector_type(4))) float f32x4;

__device__ __forceinline__ float sigf(float x) { return 1.f / (1.f + expf(-x)); }

// fp32 -> bf16 round-to-nearest-even (bit trick; no inf/nan in this workload)
__device__ __forceinline__ ushort bf16r(float x) {
    uint u = __float_as_uint(x);
    return (ushort)((u + 0x7fffu + ((u >> 16) & 1u)) >> 16);
}
__device__ __forceinline__ float bf2f(ushort h) { return __uint_as_float(((uint)h) << 16); }

// XCD-chunk swizzle (T1, m204 bijective): XCD k = bid%8 owns a contiguous chunk of w.
__device__ __forceinline__ int xcd_chunk(int bid, int nb) {
    int q = nb >> 3, r = nb & 7;
    int xcd = bid & 7, j = bid >> 3;
    return (xcd < r ? xcd * (q + 1) : r * (q + 1) + (xcd - r) * q) + j;
}

// ---------------- embedding gather + bf16 hi/lo split (state := hi+lo) ----------------
__global__ __launch_bounds__(256) void k_embed(const int* __restrict__ sent,
                                               const float* __restrict__ emb,
                                               ushort* __restrict__ oh,
                                               ushort* __restrict__ ol) {
    int idx = blockIdx.x * 256 + threadIdx.x;      // B*S*D/4 float4 slots
    int row = idx >> 7;
    int k4 = (idx & 127) << 2;
    int tok = sent[row];
    float4 v = *(const float4*)(emb + (size_t)tok * D_ + k4);
    ushort4 h, l;
    h.x = bf16r(v.x); l.x = bf16r(v.x - bf2f(h.x));
    h.y = bf16r(v.y); l.y = bf16r(v.y - bf2f(h.y));
    h.z = bf16r(v.z); l.z = bf16r(v.z - bf2f(h.z));
    h.w = bf16r(v.w); l.w = bf16r(v.w - bf2f(h.w));
    *(ushort4*)(oh + (size_t)row * D_ + k4) = h;
    *(ushort4*)(ol + (size_t)row * D_ + k4) = l;
}

// ---------------- transpose + split: dst[n][k] = src[k][n], K,N multiples of 64 ----------------
__global__ __launch_bounds__(256) void k_tsplit(const float* __restrict__ src,
                                                ushort* __restrict__ dh,
                                                ushort* __restrict__ dl,
                                                int K, int N) {
    __shared__ float t[64][65];
    int n0 = blockIdx.x * 64, k0 = blockIdx.y * 64;
    int tx = threadIdx.x & 63, ty = threadIdx.x >> 6;
    for (int i = ty; i < 64; i += 4)
        t[i][tx] = src[(size_t)(k0 + i) * N + n0 + tx];
    __syncthreads();
    for (int i = ty; i < 64; i += 4) {
        float v = t[tx][i];
        ushort h = bf16r(v);
        size_t o = (size_t)(n0 + i) * K + k0 + tx;
        dh[o] = h;
        dl[o] = bf16r(v - bf2f(h));
    }
}

// ---------------- selection hidden + logits, fused; 32 rows x 128 cols per block ----------------
// grid M/32. LDS-staged bf16x2 MFMA, K=1024, BK=32.
__global__ __launch_bounds__(256) void k_sellogit(const ushort* __restrict__ sh,
                                                  const ushort* __restrict__ sl,
                                                  const ushort* __restrict__ w1h,
                                                  const ushort* __restrict__ w1l,
                                                  const float* __restrict__ b1,
                                                  const float* __restrict__ W2,
                                                  const float* __restrict__ b2,
                                                  float* __restrict__ logits,
                                                  int N, int M, int cdiv) {
    __shared__ __align__(16) ushort sAm[2][32][40];
    __shared__ __align__(16) ushort sBm[2][128][40];
    __shared__ int rb[32];
    __shared__ float lpart[2][32];
    int w = xcd_chunk(blockIdx.x, gridDim.x);
    int r0 = w * 32;
    int tid = threadIdx.x, l = tid & 63, wid = tid >> 6;
    int rt2 = wid & 1, ch = wid >> 1;          // row 16-tile, col half (64)
    int lr = l & 15, lk = (l >> 4) << 3;

    if (tid < 32) {
        int g = r0 + tid;
        int q = (int)(((long long)g * cdiv) >> 20);      // g / N
        rb[tid] = (g + q) * 512;
    }
    __syncthreads();

    float bias[4], w2v[4];
#pragma unroll
    for (int tj = 0; tj < 4; tj++) {
        int c = ch * 64 + tj * 16 + lr;
        bias[tj] = b1[c];
        w2v[tj] = W2[c];
    }

    // A: 2 planes x 32 rows x 4 segs = 256 loads (1/thread)
    int pA = tid >> 7, remA = tid & 127;
    int rA = remA >> 2, sA = remA & 3;
    const ushort* aSrc = (pA ? sl : sh) + rb[rA] + sA * 8;
    ushort* aDst = &sAm[pA][rA][sA * 8];
    // B: 2 planes x 128 rows x 4 segs = 1024 loads (4/thread)
    const ushort* bSrc[4]; ushort* bDst[4];
#pragma unroll
    for (int j = 0; j < 4; j++) {
        int idx = tid + j * 256;
        int p = (idx >= 512) ? 1 : 0;
        int rem = idx - p * 512;
        int br = rem >> 2, s = rem & 3;
        bSrc[j] = (p ? w1l : w1h) + br * 1024 + s * 8;
        bDst[j] = &sBm[p][br][s * 8];
    }

    f32x4 z = {0.f, 0.f, 0.f, 0.f};
    f32x4 acc[4] = {z, z, z, z};
    bf16x8 gA, gB[4];

#define SSTAGE_LOAD(kk) do {                                               \
        gA = *(const bf16x8*)(aSrc + (kk));                                \
        _Pragma("unroll")                                                  \
        for (int j = 0; j < 4; j++) gB[j] = *(const bf16x8*)(bSrc[j] + (kk)); \
    } while (0)
#define SSTAGE_WRITE() do {                                                \
        *(bf16x8*)aDst = gA;                                               \
        _Pragma("unroll")                                                  \
        for (int j = 0; j < 4; j++) *(bf16x8*)bDst[j] = gB[j];             \
    } while (0)

    SSTAGE_LOAD(0);
    SSTAGE_WRITE();
    __syncthreads();

    for (int ks = 0; ks < 32; ks++) {
        if (ks < 31) SSTAGE_LOAD((ks + 1) * 32);
        bf16x8 fa[2], fb[2][4];
        {
            int ar = rt2 * 16 + lr;
            fa[0] = *(const bf16x8*)&sAm[0][ar][lk];
            fa[1] = *(const bf16x8*)&sAm[1][ar][lk];
        }
#pragma unroll
        for (int tj = 0; tj < 4; tj++) {
            int bc = ch * 64 + tj * 16 + lr;
            fb[0][tj] = *(const bf16x8*)&sBm[0][bc][lk];
            fb[1][tj] = *(const bf16x8*)&sBm[1][bc][lk];
        }
#pragma unroll
        for (int tj = 0; tj < 4; tj++) {
            acc[tj] = __builtin_amdgcn_mfma_f32_16x16x32_bf16(fa[0], fb[0][tj], acc[tj], 0, 0, 0);
            acc[tj] = __builtin_amdgcn_mfma_f32_16x16x32_bf16(fa[0], fb[1][tj], acc[tj], 0, 0, 0);
            acc[tj] = __builtin_amdgcn_mfma_f32_16x16x32_bf16(fa[1], fb[0][tj], acc[tj], 0, 0, 0);
        }
        __syncthreads();
        if (ks < 31) {
            SSTAGE_WRITE();
            __syncthreads();
        }
    }
#undef SSTAGE_LOAD
#undef SSTAGE_WRITE

    float part[4];
#pragma unroll
    for (int r = 0; r < 4; r++) {
        float s = 0.f;
#pragma unroll
        for (int tj = 0; tj < 4; tj++)
            s += tanhf(acc[tj][r] + bias[tj]) * w2v[tj];
        part[r] = s;
    }
#pragma unroll
    for (int off = 1; off < 16; off <<= 1)
#pragma unroll
        for (int r = 0; r < 4; r++)
            part[r] += __shfl_xor(part[r], off);
    if ((l & 15) == 0) {
#pragma unroll
        for (int r = 0; r < 4; r++)
            lpart[ch][rt2 * 16 + ((l >> 4) << 2) + r] = part[r];
    }
    __syncthreads();
    if (tid < 32)
        logits[r0 + tid] = lpart[0][tid] + lpart[1][tid] + b2[0];
}

// ---------------- fused softmax/cumsum + gates GEMM + treeLSTM + combine ----------------
// 128 rows x 32 comp-cols per block, 512 threads / 8 waves. LDS 48KB -> 3 blocks/CU
// (24 waves/CU, 75% occupancy ceiling) for latency hiding; grid 8N blocks.
__global__ __launch_bounds__(512) void k_compose(const ushort* __restrict__ sh,
                                                 const ushort* __restrict__ sl,
                                                 const ushort* __restrict__ wth,
                                                 const ushort* __restrict__ wtl,
                                                 const float* __restrict__ cbias,
                                                 const float* __restrict__ logits,
                                                 ushort* __restrict__ dh,
                                                 ushort* __restrict__ dl,
                                                 ushort* __restrict__ rh,
                                                 ushort* __restrict__ rl,
                                                 int N, int M, int cdiv) {
    __shared__ __align__(16) ushort sAm[2][128][40];
    __shared__ __align__(16) ushort sBm[2][160][40];
    __shared__ int rb[128];
    __shared__ float slog[256];
    __shared__ float scoef[128][3];
    int w = xcd_chunk(blockIdx.x, gridDim.x);
    int cx = w & 7, ry = w >> 3;
    int tid = threadIdx.x, l = tid & 63, wid = tid >> 6;
    int wm = wid >> 1, wn = wid & 1;           // wm 0..3 (32-row group), wn 0..1 (16 cols)
    int r0 = ry * 128;
    int cb_blk = cx * 32;
    int cbw = cb_blk + wn * 16;
    int lr = l & 15, lk = (l >> 4) << 3;

    int blo = (int)(((long long)r0 * cdiv) >> 20);             // r0 / N
    int bhi = (int)(((long long)(r0 + 127) * cdiv) >> 20);     // (r0+127) / N
    int cnt = (bhi - blo + 1) * N;                             // <= 253
    if (tid < 128) {
        int g = r0 + tid;
        int q = (int)(((long long)g * cdiv) >> 20);
        rb[tid] = (g + q) * 512;
    }
    if (tid < cnt) slog[tid] = logits[blo * N + tid];
    __syncthreads();

    if (tid < 128) {
        int g = r0 + tid;
        int b = (int)(((long long)g * cdiv) >> 20);
        int j = g - b * N;
        int o = (b - blo) * N;
        float mx = -1e30f;
        for (int k = 0; k < N; k++) mx = fmaxf(mx, slog[o + k]);
        float tot = 0.f, cs = 0.f, pj = 0.f;
        for (int k = 0; k < N; k++) {
            float e = expf(slog[o + k] - mx);
            tot += e;
            if (k <= j) cs += e;
            if (k == j) pj = e;
        }
        float inv = 1.f / tot;
        scoef[tid][0] = (tot - cs) * inv;   // copy_left
        scoef[tid][1] = (cs - pj) * inv;    // copy_right
        scoef[tid][2] = pj * inv;           // select
    }

    float bias[5];
#pragma unroll
    for (int gt = 0; gt < 5; gt++) bias[gt] = cbias[gt * 256 + cbw + lr];

    // A: 2 planes x 128 rows x 4 segs = 1024 chunks (2/thread)
    const ushort* aSrc[2]; ushort* aDst[2];
#pragma unroll
    for (int i = 0; i < 2; i++) {
        int idx = tid + i * 512;
        int p = idx >> 9, rem = idx & 511;
        int r = rem >> 2, s = rem & 3;
        aSrc[i] = (p ? sl : sh) + rb[r] + s * 8;
        aDst[i] = &sAm[p][r][s * 8];
    }
    // B: 2 planes x 160 rows x 4 segs = 1280 chunks (3/thread, guarded)
    bool bok[3];
    const ushort* bSrc[3]; ushort* bDst[3];
#pragma unroll
    for (int j = 0; j < 3; j++) {
        int idx = tid + j * 512;
        bok[j] = (idx < 1280);
        int cidx = bok[j] ? idx : 0;
        int p = (cidx >= 640) ? 1 : 0;
        int rem = cidx - p * 640;
        int br = rem >> 2, s = rem & 3;
        int col = (br >> 5) * 256 + cb_blk + (br & 31);
        bSrc[j] = (p ? wtl : wth) + col * 512 + s * 8;
        bDst[j] = &sBm[p][br][s * 8];
    }

    f32x4 z = {0.f, 0.f, 0.f, 0.f};
    f32x4 acc[2][5] = {{z, z, z, z, z}, {z, z, z, z, z}};
    bf16x8 gA[2], gB[3];

#define CSTAGE_LOAD(kk) do {                                               \
        int koff_ = ((kk) < 256) ? (kk) : (kk) + 256;                      \
        _Pragma("unroll")                                                  \
        for (int i = 0; i < 2; i++) gA[i] = *(const bf16x8*)(aSrc[i] + koff_); \
        _Pragma("unroll")                                                  \
        for (int j = 0; j < 3; j++) if (bok[j]) gB[j] = *(const bf16x8*)(bSrc[j] + (kk)); \
    } while (0)
#define CSTAGE_WRITE() do {                                                \
        _Pragma("unroll")                                                  \
        for (int i = 0; i < 2; i++) *(bf16x8*)aDst[i] = gA[i];             \
        _Pragma("unroll")                                                  \
        for (int j = 0; j < 3; j++) if (bok[j]) *(bf16x8*)bDst[j] = gB[j]; \
    } while (0)

    CSTAGE_LOAD(0);
    CSTAGE_WRITE();
    __syncthreads();

    for (int ks = 0; ks < 16; ks++) {
        if (ks < 15) CSTAGE_LOAD((ks + 1) * 32);
        bf16x8 fa[2][2], fb[2][5];
#pragma unroll
        for (int t = 0; t < 2; t++) {
            int ar = wm * 32 + t * 16 + lr;
            fa[0][t] = *(const bf16x8*)&sAm[0][ar][lk];
            fa[1][t] = *(const bf16x8*)&sAm[1][ar][lk];
        }
#pragma unroll
        for (int gt = 0; gt < 5; gt++) {
            int br = gt * 32 + wn * 16 + lr;
            fb[0][gt] = *(const bf16x8*)&sBm[0][br][lk];
            fb[1][gt] = *(const bf16x8*)&sBm[1][br][lk];
        }
#pragma unroll
        for (int gt = 0; gt < 5; gt++)
#pragma unroll
            for (int t = 0; t < 2; t++) {
                acc[t][gt] = __builtin_amdgcn_mfma_f32_16x16x32_bf16(fa[0][t], fb[0][gt], acc[t][gt], 0, 0, 0);
                acc[t][gt] = __builtin_amdgcn_mfma_f32_16x16x32_bf16(fa[0][t], fb[1][gt], acc[t][gt], 0, 0, 0);
                acc[t][gt] = __builtin_amdgcn_mfma_f32_16x16x32_bf16(fa[1][t], fb[0][gt], acc[t][gt], 0, 0, 0);
            }
        __syncthreads();
        if (ks < 15) {
            CSTAGE_WRITE();
            __syncthreads();
        }
    }
#undef CSTAGE_LOAD
#undef CSTAGE_WRITE

#pragma unroll
    for (int t = 0; t < 2; t++)
#pragma unroll
        for (int r = 0; r < 4; r++) {
            int lrow = wm * 32 + t * 16 + ((l >> 4) << 2) + r;
            int m = r0 + lrow;
            size_t sb = (size_t)rb[lrow];
            int c = cbw + lr;
            float cl = scoef[lrow][0], cr = scoef[lrow][1], sel = scoef[lrow][2];
            float h_l = bf2f(sh[sb + c])       + bf2f(sl[sb + c]);
            float c_l = bf2f(sh[sb + 256 + c]) + bf2f(sl[sb + 256 + c]);
            float h_r = bf2f(sh[sb + 512 + c]) + bf2f(sl[sb + 512 + c]);
            float c_r = bf2f(sh[sb + 768 + c]) + bf2f(sl[sb + 768 + c]);
            float gi  = acc[t][0][r] + bias[0];
            float gfl = acc[t][1][r] + bias[1];
            float gfr = acc[t][2][r] + bias[2];
            float gu  = acc[t][3][r] + bias[3];
            float go  = acc[t][4][r] + bias[4];
            float cn = sigf(gfl) * c_l + sigf(gfr) * c_r + sigf(gi) * tanhf(gu);
            float hn = sigf(go) * tanhf(cn);
            float oh = cl * h_l + cr * h_r + sel * hn;
            float oc = cl * c_l + cr * c_r + sel * cn;
            size_t ob = (size_t)m * 512 + c;
            ushort hh = bf16r(oh);
            ushort hl = bf16r(oh - bf2f(hh));
            ushort hc = bf16r(oc);
            ushort lc = bf16r(oc - bf2f(hc));
            dh[ob] = hh;       dl[ob] = hl;
            dh[ob + 256] = hc; dl[ob + 256] = lc;
            if (N == 1) {      // final layer: dense hi/lo root planes for the MLP head
                rh[ob] = hh;       rl[ob] = hl;
                rh[ob + 256] = hc; rl[ob + 256] = lc;
            }
        }
}

// ---------------- MLP layer via MFMA bf16x2: 32 rows x 128 cols per block ----------------
// grid (M/32, Nc/128). ACT: relu. SPLITOUT: write hi/lo planes, else fp32.
template <int ACT, int SPLITOUT>
__global__ __launch_bounds__(256) void k_mlp(const ushort* __restrict__ Ah,
                                             const ushort* __restrict__ Al,
                                             const ushort* __restrict__ Bh,
                                             const ushort* __restrict__ Bl,
                                             const float* __restrict__ bias,
                                             ushort* __restrict__ oh,
                                             ushort* __restrict__ ol,
                                             float* __restrict__ of,
                                             int K, int Nc) {
    __shared__ __align__(16) ushort sAm[2][32][40];
    __shared__ __align__(16) ushort sBm[2][128][40];
    int r0 = blockIdx.x * 32, cb = blockIdx.y * 128;
    int tid = threadIdx.x, l = tid & 63, wid = tid >> 6;
    int rt2 = wid & 1, ch = wid >> 1;
    int lr = l & 15, lk = (l >> 4) << 3;

    float bias4[4];
#pragma unroll
    for (int tj = 0; tj < 4; tj++) bias4[tj] = bias[cb + ch * 64 + tj * 16 + lr];

    int pA = tid >> 7, remA = tid & 127;
    int rA = remA >> 2, sA = remA & 3;
    const ushort* aSrc = (pA ? Al : Ah) + (size_t)(r0 + rA) * K + sA * 8;
    ushort* aDst = &sAm[pA][rA][sA * 8];
    const ushort* bSrc[4]; ushort* bDst[4];
#pragma unroll
    for (int j = 0; j < 4; j++) {
        int idx = tid + j * 256;
        int p = (idx >= 512) ? 1 : 0;
        int rem = idx - p * 512;
        int br = rem >> 2, s = rem & 3;
        bSrc[j] = (p ? Bl : Bh) + (size_t)(cb + br) * K + s * 8;
        bDst[j] = &sBm[p][br][s * 8];
    }

    f32x4 z = {0.f, 0.f, 0.f, 0.f};
    f32x4 acc[4] = {z, z, z, z};
    bf16x8 gA, gB[4];

#define MSTAGE_LOAD(kk) do {                                               \
        gA = *(const bf16x8*)(aSrc + (kk));                                \
        _Pragma("unroll")                                                  \
        for (int j = 0; j < 4; j++) gB[j] = *(const bf16x8*)(bSrc[j] + (kk)); \
    } while (0)
#define MSTAGE_WRITE() do {                                                \
        *(bf16x8*)aDst = gA;                                               \
        _Pragma("unroll")                                                  \
        for (int j = 0; j < 4; j++) *(bf16x8*)bDst[j] = gB[j];             \
    } while (0)

    MSTAGE_LOAD(0);
    MSTAGE_WRITE();
    __syncthreads();

    int nks = K >> 5;
    for (int ks = 0; ks < nks; ks++) {
        if (ks < nks - 1) MSTAGE_LOAD((ks + 1) * 32);
        bf16x8 fa[2], fb[2][4];
        {
            int ar = rt2 * 16 + lr;
            fa[0] = *(const bf16x8*)&sAm[0][ar][lk];
            fa[1] = *(const bf16x8*)&sAm[1][ar][lk];
        }
#pragma unroll
        for (int tj = 0; tj < 4; tj++) {
            int bc = ch * 64 + tj * 16 + lr;
            fb[0][tj] = *(const bf16x8*)&sBm[0][bc][lk];
            fb[1][tj] = *(const bf16x8*)&sBm[1][bc][lk];
        }
#pragma unroll
        for (int tj = 0; tj < 4; tj++) {
            acc[tj] = __builtin_amdgcn_mfma_f32_16x16x32_bf16(fa[0], fb[0][tj], acc[tj], 0, 0, 0);
            acc[tj] = __builtin_amdgcn_mfma_f32_16x16x32_bf16(fa[0], fb[1][tj], acc[tj], 0, 0, 0);
            acc[tj] = __builtin_amdgcn_mfma_f32_16x16x32_bf16(fa[1], fb[0][tj], acc[tj], 0, 0, 0);
        }
        __syncthreads();
        if (ks < nks - 1) {
            MSTAGE_WRITE();
            __syncthreads();
        }
    }
#undef MSTAGE_LOAD
#undef MSTAGE_WRITE

#pragma unroll
    for (int tj = 0; tj < 4; tj++)
#pragma unroll
        for (int r = 0; r < 4; r++) {
            int grow = r0 + rt2 * 16 + ((l >> 4) << 2) + r;
            int gcol = cb + ch * 64 + tj * 16 + lr;
            float v = acc[tj][r] + bias4[tj];
            if (ACT == 1) v = fmaxf(v, 0.f);
            if (SPLITOUT) {
                ushort h = bf16r(v);
                oh[(size_t)grow * Nc + gcol] = h;
                ol[(size_t)grow * Nc + gcol] = bf16r(v - bf2f(h));
            } else {
                of[(size_t)grow * Nc + gcol] = v;
            }
        }
}

// ---------------- final classifier: out[row][c] = h2[row] . Wout[:,c] + bout[c] ----------------
__global__ __launch_bounds__(64) void k_cls(const float* __restrict__ h2,
                                            const float* __restrict__ Wout,
                                            const float* __restrict__ bout,
                                            float* __restrict__ out) {
    int row = blockIdx.x, lane = threadIdx.x;
    float s0 = 0.f, s1 = 0.f, s2 = 0.f;
    for (int k = lane; k < 1024; k += 64) {
        float v = h2[(size_t)row * 1024 + k];
        s0 += v * Wout[k * 3 + 0];
        s1 += v * Wout[k * 3 + 1];
        s2 += v * Wout[k * 3 + 2];
    }
#pragma unroll
    for (int o = 32; o >= 1; o >>= 1) {
        s0 += __shfl_down(s0, o);
        s1 += __shfl_down(s1, o);
        s2 += __shfl_down(s2, o);
    }
    if (lane == 0) {
        out[row * 3 + 0] = s0 + bout[0];
        out[row * 3 + 1] = s1 + bout[1];
        out[row * 3 + 2] = s2 + bout[2];
    }
}

extern "C" void kernel_launch(void* const* d_in, const int* in_sizes, int n_in,
                              void* d_out, int out_size, void* d_ws, size_t ws_size,
                              hipStream_t stream) {
    const int*   sent     = (const int*)d_in[0];
    // d_in[1] transitions: unused by reference
    const float* emb      = (const float*)d_in[2];
    const float* comp_W   = (const float*)d_in[3];
    const float* comp_b   = (const float*)d_in[4];
    const float* sel_W1   = (const float*)d_in[5];
    const float* sel_b1   = (const float*)d_in[6];
    const float* sel_W2   = (const float*)d_in[7];
    const float* sel_b2   = (const float*)d_in[8];
    const float* mlp_W0   = (const float*)d_in[9];
    const float* mlp_b0   = (const float*)d_in[10];
    const float* mlp_W1   = (const float*)d_in[11];
    const float* mlp_b1   = (const float*)d_in[12];
    const float* mlp_Wout = (const float*)d_in[13];
    const float* mlp_bout = (const float*)d_in[14];
    float* outp = (float*)d_out;

    char* p = (char*)d_ws;
    ushort* sh0  = (ushort*)p; p += (size_t)B_ * S_ * D_ * 2;
    ushort* sl0  = (ushort*)p; p += (size_t)B_ * S_ * D_ * 2;
    ushort* sh1  = (ushort*)p; p += (size_t)B_ * S_ * D_ * 2;
    ushort* sl1  = (ushort*)p; p += (size_t)B_ * S_ * D_ * 2;
    ushort* wth  = (ushort*)p; p += (size_t)1280 * 512 * 2;
    ushort* wtl  = (ushort*)p; p += (size_t)1280 * 512 * 2;
    ushort* w1th = (ushort*)p; p += (size_t)128 * 1024 * 2;
    ushort* w1tl = (ushort*)p; p += (size_t)128 * 1024 * 2;
    ushort* w0th = (ushort*)p; p += (size_t)1024 * 512 * 2;
    ushort* w0tl = (ushort*)p; p += (size_t)1024 * 512 * 2;
    ushort* w1mh = (ushort*)p; p += (size_t)1024 * 1024 * 2;
    ushort* w1ml = (ushort*)p; p += (size_t)1024 * 1024 * 2;
    float*  logits = (float*)p; p += (size_t)B_ * 63 * 4;
    ushort* rh   = (ushort*)p; p += (size_t)B_ * D_ * 2;
    ushort* rl   = (ushort*)p; p += (size_t)B_ * D_ * 2;
    ushort* h1h  = (ushort*)p; p += (size_t)B_ * MLPD_ * 2;
    ushort* h1l  = (ushort*)p; p += (size_t)B_ * MLPD_ * 2;
    float*  h2   = (float*)p;  p += (size_t)B_ * MLPD_ * 4;

    k_embed<<<dim3(4096), dim3(256), 0, stream>>>(sent, emb, sh0, sl0);
    k_tsplit<<<dim3(20, 8), dim3(256), 0, stream>>>(comp_W, wth, wtl, 512, 1280);
    k_tsplit<<<dim3(2, 16), dim3(256), 0, stream>>>(sel_W1, w1th, w1tl, 1024, 128);
    k_tsplit<<<dim3(16, 8), dim3(256), 0, stream>>>(mlp_W0, w0th, w0tl, 512, 1024);
    k_tsplit<<<dim3(16, 16), dim3(256), 0, stream>>>(mlp_W1, w1mh, w1ml, 1024, 1024);

    ushort* shs = sh0; ushort* sls = sl0;
    ushort* shd = sh1; ushort* sld = sl1;
    for (int L = S_; L >= 2; --L) {
        int N = L - 1;
        int M = B_ * N;
        int cdiv = (1048576 + N - 1) / N;
        k_sellogit<<<dim3(M / 32), dim3(256), 0, stream>>>(shs, sls, w1th, w1tl, sel_b1,
                                                           sel_W2, sel_b2, logits, N, M, cdiv);
        k_compose<<<dim3(8 * (M / 128)), dim3(512), 0, stream>>>(shs, sls, wth, wtl, comp_b, logits,
                                                                 shd, sld, rh, rl, N, M, cdiv);
        ushort* th = shs; shs = shd; shd = th;
        ushort* tl = sls; sls = sld; sld = tl;
    }

    k_mlp<1, 1><<<dim3(4, 8), dim3(256), 0, stream>>>(rh, rl, w0th, w0tl, mlp_b0,
                                                      h1h, h1l, nullptr, 512, MLPD_);
    k_mlp<1, 0><<<dim3(4, 8), dim3(256), 0, stream>>>(h1h, h1l, w1mh, w1ml, mlp_b1,
                                                      nullptr, nullptr, h2, 1024, MLPD_);
    k_cls<<<dim3(B_), dim3(64), 0, stream>>>(h2, mlp_Wout, mlp_bout, outp);
}